// Round 5
// baseline (269.010 us; speedup 1.0000x reference)
//
#include <hip/hip_runtime.h>
#include <math.h>

// ---------------- types ----------------
typedef __attribute__((ext_vector_type(8))) short short8;
typedef __attribute__((ext_vector_type(4))) float f32x4;

#define NB 2
#define LQ 2048
#define LK 2048
#define DM 1024
#define NH 16
#define HD 64

__device__ __forceinline__ unsigned short f2bf(float f) {
    unsigned u = __builtin_bit_cast(unsigned, f);
    u = (u + 0x7FFFu + ((u >> 16) & 1u)) >> 16;
    return (unsigned short)u;
}

__device__ __forceinline__ void gload16(const void* g, void* l) {
    __builtin_amdgcn_global_load_lds(
        (const __attribute__((address_space(1))) void*)g,
        (__attribute__((address_space(3))) void*)l, 16, 0, 0);
}

__device__ __forceinline__ unsigned cvtpk(float a, float b) {
    unsigned r;
    asm("v_cvt_pk_bf16_f32 %0, %1, %2" : "=v"(r) : "v"(a), "v"(b));
    return r;
}

// XOR-swizzled LDS accessors for [R][64] u16 tiles (row stride 128 B).
__device__ __forceinline__ short8 lds_load8(const unsigned short* base, int row, int col) {
    int byte = (row * 128 + col * 2) ^ ((row & 7) << 4);
    return *(const short8*)((const char*)base + byte);
}

// ---------------- convert f32 -> bf16 ----------------
__global__ __launch_bounds__(256) void convertk(
    const float* __restrict__ q, const float* __restrict__ k,
    const float* __restrict__ wq, const float* __restrict__ wk,
    const float* __restrict__ wv, unsigned short* __restrict__ dst)
{
    long i4 = (long)blockIdx.x * 256 + threadIdx.x;
    long e = i4 * 4;
    if (e >= 11534336L) return;
    const float* src; long off;
    if (e < 4194304L)       { src = q;  off = e; }
    else if (e < 8388608L)  { src = k;  off = e - 4194304L; }
    else if (e < 9437184L)  { src = wq; off = e - 8388608L; }
    else if (e < 10485760L) { src = wk; off = e - 9437184L; }
    else                    { src = wv; off = e - 10485760L; }
    float4 v = *(const float4*)(src + off);
    ushort4 r;
    r.x = f2bf(v.x); r.y = f2bf(v.y); r.z = f2bf(v.z); r.w = f2bf(v.w);
    *(ushort4*)(dst + e) = r;
}

// ---------------- projection GEMM: C = A * B^T  (bf16, row-major, K=1024, BK=64) ----------------
// LDS tiles [128][64] u16, XOR-swizzled (both-sides: pre-swizzled global source col +
// swizzled reads). Each gload16 issue = 8 contiguous rows (64 lanes x 16 B).
__global__ __launch_bounds__(256) void gemm3(
    const unsigned short* __restrict__ Qb, const unsigned short* __restrict__ Kb,
    const unsigned short* __restrict__ Wqb, const unsigned short* __restrict__ Wkb,
    const unsigned short* __restrict__ Wvb,
    unsigned short* __restrict__ Qp, unsigned short* __restrict__ Kp, unsigned short* __restrict__ Vp)
{
    const unsigned short *A, *B;
    unsigned short* C;
    int z = blockIdx.z;
    if (z == 0)      { A = Qb; B = Wqb; C = Qp; }
    else if (z == 1) { A = Kb; B = Wkb; C = Kp; }
    else             { A = Kb; B = Wvb; C = Vp; }
    const int K = DM, NN = DM;
    __shared__ unsigned short As[8192];  // [128][64] swizzled
    __shared__ unsigned short Bs[8192];  // [128][64] swizzled
    int t = threadIdx.x, wave = t >> 6, lane = t & 63;
    int bm = blockIdx.x * 128, bn = blockIdx.y * 128;
    int wr = (wave >> 1) * 64, wc = (wave & 1) * 64;
    int srow = lane >> 3;                         // 0..7 within an 8-row stripe
    int scol = ((lane & 7) << 3) ^ (srow << 3);   // pre-swizzled source column (elems)
    int frow = lane & 15, fk = (lane >> 4) * 8;
    f32x4 zero = {0.f, 0.f, 0.f, 0.f};
    f32x4 acc[4][4];
    for (int i = 0; i < 4; i++) for (int j = 0; j < 4; j++) acc[i][j] = zero;

    for (int k0 = 0; k0 < K; k0 += 64) {
#pragma unroll
        for (int i = 0; i < 4; i++) {
            int r0 = wave * 32 + i * 8;           // stripe base row (multiple of 8)
            gload16(A + (size_t)(bm + r0 + srow) * K + k0 + scol, &As[r0 * 64]);
            gload16(B + (size_t)(bn + r0 + srow) * K + k0 + scol, &Bs[r0 * 64]);
        }
        __syncthreads();
#pragma unroll
        for (int half = 0; half < 2; half++) {
            short8 af[4], bfr[4];
#pragma unroll
            for (int i = 0; i < 4; i++) af[i]  = lds_load8(As, wr + i * 16 + frow, half * 32 + fk);
#pragma unroll
            for (int j = 0; j < 4; j++) bfr[j] = lds_load8(Bs, wc + j * 16 + frow, half * 32 + fk);
#pragma unroll
            for (int i = 0; i < 4; i++)
#pragma unroll
                for (int j = 0; j < 4; j++)
                    acc[i][j] = __builtin_amdgcn_mfma_f32_16x16x32_bf16(af[i], bfr[j], acc[i][j], 0, 0, 0);
        }
        __syncthreads();
    }
    int ccol = lane & 15, crow = (lane >> 4) * 4;
#pragma unroll
    for (int i = 0; i < 4; i++)
#pragma unroll
        for (int j = 0; j < 4; j++) {
            int col = bn + wc + j * 16 + ccol;
#pragma unroll
            for (int r = 0; r < 4; r++) {
                int row = bm + wr + i * 16 + crow + r;
                C[(size_t)row * NN + col] = f2bf(acc[i][j][r]);
            }
        }
}

// ---------------- transpose V (per sentence 2048x1024 -> 1024x2048) ----------------
__global__ __launch_bounds__(256) void transposek(const unsigned short* __restrict__ V,
                                                  unsigned short* __restrict__ Vt)
{
    __shared__ unsigned short tile[64][65];
    int n = blockIdx.z;
    int k0 = blockIdx.x * 64, d0 = blockIdx.y * 64;
    int t = threadIdx.x;
#pragma unroll
    for (int it = 0; it < 2; it++) {
        int r = (t >> 3) + it * 32, c = (t & 7) * 8;
        short8 v = *(const short8*)&V[((size_t)(n * LK + k0 + r)) * DM + d0 + c];
#pragma unroll
        for (int j = 0; j < 8; j++) tile[r][c + j] = (unsigned short)v[j];
    }
    __syncthreads();
#pragma unroll
    for (int it = 0; it < 2; it++) {
        int r2 = (t >> 3) + it * 32, c2 = (t & 7) * 8;
        short8 v;
#pragma unroll
        for (int j = 0; j < 8; j++) v[j] = (short)tile[c2 + j][r2];
        *(short8*)&Vt[((size_t)(n * DM + d0 + r2)) * LK + k0 + c2] = v;
    }
}

// ---------------- flash attention (barrier-free, direct-from-L2 K/V frags) ----------------
// Block = 2 waves. Paired q-tiles (xs, 63-xs) share one k-loop -> uniform ~33 phase-units.
// K/V per (n,h) is 256 KB each (L2-resident; 4 heads/XCD = 2 MB < 4 MB L2) -> no LDS
// staging, no __syncthreads. Swapped mfma(K,Q): lane holds S-col for ONE q (q = lane&15).

__device__ __forceinline__ void softmax_pack(
    f32x4 (&sv)[4], unsigned short* PsW,
    int qw, int k0, int vlen, float c2,
    f32x4 (&o)[4], float& m_run, float& l_run, int lane)
{
    const int c = lane & 15, g = lane >> 4;
    bool full = (k0 + 63 <= qw) && (k0 + 64 <= vlen);
    if (!full) {
        int q = qw + c;
#pragma unroll
        for (int kt = 0; kt < 4; kt++)
#pragma unroll
            for (int r = 0; r < 4; r++) {
                int kg = k0 + kt * 16 + g * 4 + r;
                if (kg > q || kg >= vlen) sv[kt][r] = -INFINITY;
            }
    }
    float mx = fmaxf(fmaxf(sv[0][0], sv[0][1]), fmaxf(sv[0][2], sv[0][3]));
#pragma unroll
    for (int kt = 1; kt < 4; kt++)
        mx = fmaxf(mx, fmaxf(fmaxf(sv[kt][0], sv[kt][1]), fmaxf(sv[kt][2], sv[kt][3])));
    mx = fmaxf(mx, __shfl_xor(mx, 16));
    mx = fmaxf(mx, __shfl_xor(mx, 32));      // per-q max over whole tile (finite for all live q)
    // defer-max (T13): only rescale when the max grew by > 8/c2 (P bounded by 2^8)
    if (__any((mx - m_run) * c2 > 8.0f)) {
        float mn = fmaxf(m_run, mx);
        float al = __builtin_amdgcn_exp2f((m_run - mn) * c2);
        float alr[4];
#pragma unroll
        for (int r = 0; r < 4; r++) alr[r] = __shfl(al, 4 * g + r);
#pragma unroll
        for (int dt = 0; dt < 4; dt++)
#pragma unroll
            for (int r = 0; r < 4; r++) o[dt][r] *= alr[r];
        l_run *= al;
        m_run = mn;
    }
    float ssum = 0.f;
#pragma unroll
    for (int kt = 0; kt < 4; kt++)
#pragma unroll
        for (int r = 0; r < 4; r++) {
            float p = __builtin_amdgcn_exp2f((sv[kt][r] - m_run) * c2);
            sv[kt][r] = p;
            ssum += p;
        }
    ssum += __shfl_xor(ssum, 16);
    ssum += __shfl_xor(ssum, 32);
    l_run += ssum;
#pragma unroll
    for (int kt = 0; kt < 4; kt++) {
        uint2 pw;
        pw.x = cvtpk(sv[kt][0], sv[kt][1]);
        pw.y = cvtpk(sv[kt][2], sv[kt][3]);
        int byte = (c * 128 + (kt * 16 + g * 4) * 2) ^ ((c & 7) << 4);
        *(uint2*)((char*)PsW + byte) = pw;
    }
}

__device__ __forceinline__ void attn_epilogue(float* out, const f32x4 (&o)[4], float l_run,
                                              int n, int h, int qw, int lane)
{
    int c = lane & 15, g = lane >> 4;
    float lr[4];
#pragma unroll
    for (int r = 0; r < 4; r++) lr[r] = __shfl(l_run, 4 * g + r);
#pragma unroll
    for (int dt = 0; dt < 4; dt++)
#pragma unroll
        for (int r = 0; r < 4; r++) {
            int q = qw + 4 * g + r;
            int d = h * HD + dt * 16 + c;
            out[((size_t)n * LQ + q) * DM + d] = o[dt][r] / lr[r];
        }
}

__global__ __launch_bounds__(128, 3) void attnk(
    const unsigned short* __restrict__ Qp, const unsigned short* __restrict__ Kp,
    const unsigned short* __restrict__ Vt, const unsigned char* __restrict__ pm,
    float* __restrict__ out)
{
    __shared__ unsigned short Ps[2][2][1024];  // [wave][phase][16 q][64 k] swizzled
    int t = threadIdx.x, w = t >> 6, lane = t & 63;
    // XCD swizzle: same (n,h) -> same XCD; tile index rotated per round
    int bid = blockIdx.x;
    int r3 = bid >> 8;
    int xs = ((bid >> 3) + (r3 << 3)) & 31;
    int y  = (bid & 7) * 4 + r3;
    int n = y >> 4, h = y & 15;
    int qwA = xs * 32 + 16 * w;
    int qwB = (63 - xs) * 32 + 16 * w;
    const int c = lane & 15, g = lane >> 4, fk = g * 8;

    // valid length: count zero bytes of padding mask (wave-local reduce, no LDS)
    int vlen;
    {
        const uint4* pmv = (const uint4*)(pm + (size_t)n * LK);
        uint4 a = pmv[lane * 2], b = pmv[lane * 2 + 1];
        int ones = __popc(a.x) + __popc(a.y) + __popc(a.z) + __popc(a.w)
                 + __popc(b.x) + __popc(b.y) + __popc(b.z) + __popc(b.w);
        int zeros = 32 - ones;
#pragma unroll
        for (int off = 1; off < 64; off <<= 1) zeros += __shfl_xor(zeros, off);
        vlen = zeros;
    }
    float c2 = 1.4426950408889634f / sqrtf((float)vlen);
    int kvt = (vlen + 63) >> 6;
    int ntA = min((xs >> 1) + 1, kvt);
    int ntB = min(((63 - xs) >> 1) + 1, kvt);

    const unsigned short* Kbase = Kp + (size_t)n * LK * DM + h * HD;     // + k*DM
    const unsigned short* Vbase = Vt + ((size_t)n * DM + h * HD) * LK;   // + d*LK

    // Q fragments (B-operand: row = lane&15 -> q = qw + c, cols d = fk..)
    const unsigned short* qA = Qp + (size_t)(n * LQ + qwA + c) * DM + h * HD;
    const unsigned short* qB = Qp + (size_t)(n * LQ + qwB + c) * DM + h * HD;
    short8 qA0 = *(const short8*)(qA + fk), qA1 = *(const short8*)(qA + 32 + fk);
    short8 qB0 = *(const short8*)(qB + fk), qB1 = *(const short8*)(qB + 32 + fk);

    f32x4 zero = {0.f, 0.f, 0.f, 0.f};
    f32x4 oA[4] = {zero, zero, zero, zero};
    f32x4 oB[4] = {zero, zero, zero, zero};
    float mA = -INFINITY, lA = 0.f, mB = -INFINITY, lB = 0.f;
    unsigned short* PsA = &Ps[w][0][0];
    unsigned short* PsB = &Ps[w][1][0];

    for (int ti = 0; ti < ntB; ti++) {
        int k0 = ti * 64;
        bool doA = ti < ntA;
        const unsigned short* Kt = Kbase + (size_t)k0 * DM;
        f32x4 svA[4], svB[4];
        // QK^T: A-frag = K rows (k = kt*16+c), direct from L2
        __builtin_amdgcn_s_setprio(1);
#pragma unroll
        for (int kt = 0; kt < 4; kt++) {
            const unsigned short* kr = Kt + (size_t)(kt * 16 + c) * DM;
            short8 kf0 = *(const short8*)(kr + fk);
            short8 kf1 = *(const short8*)(kr + 32 + fk);
            f32x4 zB = zero;
            zB = __builtin_amdgcn_mfma_f32_16x16x32_bf16(kf0, qB0, zB, 0, 0, 0);
            zB = __builtin_amdgcn_mfma_f32_16x16x32_bf16(kf1, qB1, zB, 0, 0, 0);
            svB[kt] = zB;
            if (doA) {
                f32x4 zA = zero;
                zA = __builtin_amdgcn_mfma_f32_16x16x32_bf16(kf0, qA0, zA, 0, 0, 0);
                zA = __builtin_amdgcn_mfma_f32_16x16x32_bf16(kf1, qA1, zA, 0, 0, 0);
                svA[kt] = zA;
            }
        }
        __builtin_amdgcn_s_setprio(0);

        if (doA) softmax_pack(svA, PsA, qwA, k0, vlen, c2, oA, mA, lA, lane);
        softmax_pack(svB, PsB, qwB, k0, vlen, c2, oB, mB, lB, lane);

        // PV: B-frag = V^T rows (d = dt*16+c), direct from L2; P from wave-private LDS
        __builtin_amdgcn_s_setprio(1);
#pragma unroll
        for (int ks = 0; ks < 2; ks++) {
            short8 apB = lds_load8(PsB, c, ks * 32 + fk);
            short8 apA;
            if (doA) apA = lds_load8(PsA, c, ks * 32 + fk);
#pragma unroll
            for (int dt = 0; dt < 4; dt++) {
                short8 bv = *(const short8*)(Vbase + (size_t)(dt * 16 + c) * LK + k0 + ks * 32 + fk);
                oB[dt] = __builtin_amdgcn_mfma_f32_16x16x32_bf16(apB, bv, oB[dt], 0, 0, 0);
                if (doA) oA[dt] = __builtin_amdgcn_mfma_f32_16x16x32_bf16(apA, bv, oA[dt], 0, 0, 0);
            }
        }
        __builtin_amdgcn_s_setprio(0);
    }
    attn_epilogue(out, oA, lA, n, h, qwA, lane);
    attn_epilogue(out, oB, lB, n, h, qwB, lane);
}

// ---------------- launch ----------------
extern "C" void kernel_launch(void* const* d_in, const int* in_sizes, int n_in,
                              void* d_out, int out_size, void* d_ws, size_t ws_size,
                              hipStream_t stream) {
    const float* query = (const float*)d_in[0];
    const float* key   = (const float*)d_in[1];
    const float* Wq    = (const float*)d_in[2];
    const float* Wk    = (const float*)d_in[3];
    const float* Wv    = (const float*)d_in[4];
    const unsigned char* pmask = (const unsigned char*)d_in[6];
    float* out = (float*)d_out;

    char* ws = (char*)d_ws;
    unsigned short* bfbase = (unsigned short*)ws;
    unsigned short* Qb  = bfbase;                          // 4096x1024
    unsigned short* Kb  = bfbase + 4194304L;               // 4096x1024
    unsigned short* Wqb = bfbase + 8388608L;
    unsigned short* Wkb = bfbase + 9437184L;
    unsigned short* Wvb = bfbase + 10485760L;
    unsigned short* Qp  = (unsigned short*)(ws + 23068672L);
    unsigned short* Kp  = (unsigned short*)(ws + 31457280L);
    unsigned short* Vp  = (unsigned short*)(ws + 39845888L);
    unsigned short* Vt  = (unsigned short*)(ws + 48234496L);   // [2][1024][2048]

    convertk<<<11264, 256, 0, stream>>>(query, key, Wq, Wk, Wv, bfbase);
    gemm3<<<dim3(32, 8, 3), 256, 0, stream>>>(Qb, Kb, Wqb, Wkb, Wvb, Qp, Kp, Vp);
    transposek<<<dim3(32, 16, 2), 256, 0, stream>>>(Vp, Vt);
    attnk<<<1024, 128, 0, stream>>>(Qp, Kp, Vt, pmask, out);
}

// Round 6
// 243.141 us; speedup vs baseline: 1.1064x; 1.1064x over previous
//
#include <hip/hip_runtime.h>
#include <math.h>

// ---------------- types ----------------
typedef __attribute__((ext_vector_type(8))) short short8;
typedef __attribute__((ext_vector_type(4))) float f32x4;

#define NB 2
#define LQ 2048
#define LK 2048
#define DM 1024
#define NH 16
#define HD 64
#define KB 32   // attn k-tile

__device__ __forceinline__ unsigned short f2bf(float f) {
    unsigned u = __builtin_bit_cast(unsigned, f);
    u = (u + 0x7FFFu + ((u >> 16) & 1u)) >> 16;
    return (unsigned short)u;
}

__device__ __forceinline__ void gload16(const void* g, void* l) {
    __builtin_amdgcn_global_load_lds(
        (const __attribute__((address_space(1))) void*)g,
        (__attribute__((address_space(3))) void*)l, 16, 0, 0);
}

__device__ __forceinline__ unsigned cvtpk(float a, float b) {
    unsigned r;
    asm("v_cvt_pk_bf16_f32 %0, %1, %2" : "=v"(r) : "v"(a), "v"(b));
    return r;
}

// swizzled accessor for [R][32] u16 LDS tiles (row stride 64 B): slot ^= row&3
__device__ __forceinline__ short8 lds32(const unsigned short* base, int row, int col) {
    int byte = (row * 64 + col * 2) ^ ((row & 3) << 4);
    return *(const short8*)((const char*)base + byte);
}

// ---------------- convert f32 -> bf16 ----------------
__global__ __launch_bounds__(256) void convertk(
    const float* __restrict__ q, const float* __restrict__ k,
    const float* __restrict__ wq, const float* __restrict__ wk,
    const float* __restrict__ wv, unsigned short* __restrict__ dst)
{
    long i4 = (long)blockIdx.x * 256 + threadIdx.x;
    long e = i4 * 4;
    if (e >= 11534336L) return;
    const float* src; long off;
    if (e < 4194304L)       { src = q;  off = e; }
    else if (e < 8388608L)  { src = k;  off = e - 4194304L; }
    else if (e < 9437184L)  { src = wq; off = e - 8388608L; }
    else if (e < 10485760L) { src = wk; off = e - 9437184L; }
    else                    { src = wv; off = e - 10485760L; }
    float4 v = *(const float4*)(src + off);
    ushort4 r;
    r.x = f2bf(v.x); r.y = f2bf(v.y); r.z = f2bf(v.z); r.w = f2bf(v.w);
    *(ushort4*)(dst + e) = r;
}

// ---------------- projection GEMM: C = A * B^T (bf16, K=1024, BK=32, LDS dbuf) ----------------
__device__ __forceinline__ void gemm_stage(
    const unsigned short* A, const unsigned short* B,
    unsigned short* As, unsigned short* Bs,
    int bm, int bn, int k0, int wave, int srow, int scol)
{
    const int K = DM;
    int i0 = wave, i1 = wave + 4;
    gload16(A + (size_t)(bm + i0 * 16 + srow) * K + k0 + scol, As + i0 * 512);
    gload16(B + (size_t)(bn + i0 * 16 + srow) * K + k0 + scol, Bs + i0 * 512);
    gload16(A + (size_t)(bm + i1 * 16 + srow) * K + k0 + scol, As + i1 * 512);
    gload16(B + (size_t)(bn + i1 * 16 + srow) * K + k0 + scol, Bs + i1 * 512);
}

__global__ __launch_bounds__(256) void gemm3(
    const unsigned short* __restrict__ Qb, const unsigned short* __restrict__ Kb,
    const unsigned short* __restrict__ Wqb, const unsigned short* __restrict__ Wkb,
    const unsigned short* __restrict__ Wvb,
    unsigned short* __restrict__ Qp, unsigned short* __restrict__ Kp, unsigned short* __restrict__ Vp)
{
    const unsigned short *A, *B;
    unsigned short* C;
    int z = blockIdx.z;
    if (z == 0)      { A = Qb; B = Wqb; C = Qp; }
    else if (z == 1) { A = Kb; B = Wkb; C = Kp; }
    else             { A = Kb; B = Wvb; C = Vp; }
    const int NN = DM;
    __shared__ unsigned short As[2][4096];  // [128][32] swizzled
    __shared__ unsigned short Bs[2][4096];
    int t = threadIdx.x, wave = t >> 6, lane = t & 63;
    int bm = blockIdx.x * 128, bn = blockIdx.y * 128;
    int wr = (wave >> 1) * 64, wc = (wave & 1) * 64;
    int srow = lane >> 2;                        // 0..15 within 16-row stripe
    int scol = ((lane & 3) ^ (srow & 3)) << 3;   // pre-swizzled source col (elems)
    int frow = lane & 15, fk = (lane >> 4) * 8;
    f32x4 zero = {0.f, 0.f, 0.f, 0.f};
    f32x4 acc[4][4];
    for (int i = 0; i < 4; i++) for (int j = 0; j < 4; j++) acc[i][j] = zero;

    gemm_stage(A, B, As[0], Bs[0], bm, bn, 0, wave, srow, scol);
    __syncthreads();
    for (int s = 0; s < 32; s++) {
        int cur = s & 1;
        if (s + 1 < 32)
            gemm_stage(A, B, As[cur ^ 1], Bs[cur ^ 1], bm, bn, (s + 1) * 32, wave, srow, scol);
        short8 af[4], bfr[4];
#pragma unroll
        for (int i = 0; i < 4; i++) af[i]  = lds32(As[cur], wr + i * 16 + frow, fk);
#pragma unroll
        for (int j = 0; j < 4; j++) bfr[j] = lds32(Bs[cur], wc + j * 16 + frow, fk);
#pragma unroll
        for (int i = 0; i < 4; i++)
#pragma unroll
            for (int j = 0; j < 4; j++)
                acc[i][j] = __builtin_amdgcn_mfma_f32_16x16x32_bf16(af[i], bfr[j], acc[i][j], 0, 0, 0);
        __syncthreads();
    }
    int ccol = lane & 15, crow = (lane >> 4) * 4;
#pragma unroll
    for (int i = 0; i < 4; i++)
#pragma unroll
        for (int j = 0; j < 4; j++) {
            int col = bn + wc + j * 16 + ccol;
#pragma unroll
            for (int r = 0; r < 4; r++) {
                int row = bm + wr + i * 16 + crow + r;
                C[(size_t)row * NN + col] = f2bf(acc[i][j][r]);
            }
        }
}

// ---------------- transpose V (per sentence 2048x1024 -> 1024x2048) ----------------
__global__ __launch_bounds__(256) void transposek(const unsigned short* __restrict__ V,
                                                  unsigned short* __restrict__ Vt)
{
    __shared__ unsigned short tile[64][65];
    int n = blockIdx.z;
    int k0 = blockIdx.x * 64, d0 = blockIdx.y * 64;
    int t = threadIdx.x;
#pragma unroll
    for (int it = 0; it < 2; it++) {
        int r = (t >> 3) + it * 32, c = (t & 7) * 8;
        short8 v = *(const short8*)&V[((size_t)(n * LK + k0 + r)) * DM + d0 + c];
#pragma unroll
        for (int j = 0; j < 8; j++) tile[r][c + j] = (unsigned short)v[j];
    }
    __syncthreads();
#pragma unroll
    for (int it = 0; it < 2; it++) {
        int r2 = (t >> 3) + it * 32, c2 = (t & 7) * 8;
        short8 v;
#pragma unroll
        for (int j = 0; j < 8; j++) v[j] = (short)tile[c2 + j][r2];
        *(short8*)&Vt[((size_t)(n * DM + d0 + r2)) * LK + k0 + c2] = v;
    }
}

// ---------------- flash attention: 1-wave blocks, register-dbuf K/V pipeline ----------------
// Wave owns paired 16-row q-tiles (xs, 127-xs); k-tiles of 32 loaded one tile ahead
// into named register buffers (compiler-managed vmcnt waits; no barriers, no LDS staging).
// Swapped mfma(K,Q): lane holds S-column for one q (q = qw + (lane&15)).

struct KVreg {
    short8 k0, k1, k2, k3;   // K rows {c, 16+c} x d-halves {0..32, 32..64}
    short8 v0, v1, v2, v3;   // V^T rows {c, 16+c, 32+c, 48+c}, k-cols of this tile
};

__device__ __forceinline__ void ld_kv(KVreg& b, const unsigned short* Kt,
                                      const unsigned short* Vbase, int k0, int c, int fk)
{
    const unsigned short* kr0 = Kt + (size_t)(k0 + c) * DM;
    const unsigned short* kr1 = Kt + (size_t)(k0 + 16 + c) * DM;
    b.k0 = *(const short8*)(kr0 + fk);
    b.k1 = *(const short8*)(kr0 + 32 + fk);
    b.k2 = *(const short8*)(kr1 + fk);
    b.k3 = *(const short8*)(kr1 + 32 + fk);
    const unsigned short* vr = Vbase + k0 + fk;
    b.v0 = *(const short8*)(vr + (size_t)(c) * LK);
    b.v1 = *(const short8*)(vr + (size_t)(16 + c) * LK);
    b.v2 = *(const short8*)(vr + (size_t)(32 + c) * LK);
    b.v3 = *(const short8*)(vr + (size_t)(48 + c) * LK);
}

__device__ __forceinline__ void phase32(
    const KVreg& b, const short8& q0, const short8& q1, unsigned short* PsW,
    int qw, int k0, int vlen, float c2,
    f32x4 (&o)[4], float& m_run, float& l_run, int c, int g)
{
    f32x4 zero = {0.f, 0.f, 0.f, 0.f};
    f32x4 s0 = zero, s1 = zero;
    s0 = __builtin_amdgcn_mfma_f32_16x16x32_bf16(b.k0, q0, s0, 0, 0, 0);
    s0 = __builtin_amdgcn_mfma_f32_16x16x32_bf16(b.k1, q1, s0, 0, 0, 0);
    s1 = __builtin_amdgcn_mfma_f32_16x16x32_bf16(b.k2, q0, s1, 0, 0, 0);
    s1 = __builtin_amdgcn_mfma_f32_16x16x32_bf16(b.k3, q1, s1, 0, 0, 0);
    // s0[r] = S[k0+4g+r][qw+c], s1[r] = S[k0+16+4g+r][qw+c]
    bool full = (k0 + KB - 1 <= qw) && (k0 + KB <= vlen);
    if (!full) {
        int q = qw + c;
#pragma unroll
        for (int r = 0; r < 4; r++) {
            int kg0 = k0 + 4 * g + r, kg1 = kg0 + 16;
            if (kg0 > q || kg0 >= vlen) s0[r] = -INFINITY;
            if (kg1 > q || kg1 >= vlen) s1[r] = -INFINITY;
        }
    }
    float mx = fmaxf(fmaxf(fmaxf(s0[0], s0[1]), fmaxf(s0[2], s0[3])),
                     fmaxf(fmaxf(s1[0], s1[1]), fmaxf(s1[2], s1[3])));
    mx = fmaxf(mx, __shfl_xor(mx, 16));
    mx = fmaxf(mx, __shfl_xor(mx, 32));
    // defer-max (T13): rescale only when max grew enough to matter (P bounded by 2^8)
    if (__any((mx - m_run) * c2 > 8.0f)) {
        float mn = fmaxf(m_run, mx);
        float al = __builtin_amdgcn_exp2f((m_run - mn) * c2);
        float alr[4];
#pragma unroll
        for (int r = 0; r < 4; r++) alr[r] = __shfl(al, 4 * g + r);
#pragma unroll
        for (int dt = 0; dt < 4; dt++)
#pragma unroll
            for (int r = 0; r < 4; r++) o[dt][r] *= alr[r];
        l_run *= al;
        m_run = mn;
    }
    float ssum = 0.f;
#pragma unroll
    for (int r = 0; r < 4; r++) {
        float p0 = __builtin_amdgcn_exp2f((s0[r] - m_run) * c2);
        float p1 = __builtin_amdgcn_exp2f((s1[r] - m_run) * c2);
        s0[r] = p0; s1[r] = p1;
        ssum += p0 + p1;
    }
    ssum += __shfl_xor(ssum, 16);
    ssum += __shfl_xor(ssum, 32);
    l_run += ssum;
    // pack P -> wave-private LDS [16 q][32 k], row stride 80 B
    uint2 pw0, pw1;
    pw0.x = cvtpk(s0[0], s0[1]); pw0.y = cvtpk(s0[2], s0[3]);
    pw1.x = cvtpk(s1[0], s1[1]); pw1.y = cvtpk(s1[2], s1[3]);
    *(uint2*)((char*)PsW + c * 80 + 8 * g)      = pw0;
    *(uint2*)((char*)PsW + c * 80 + 32 + 8 * g) = pw1;
    // PV: A = P row c (k-cols 8g..8g+8), B = V^T rows dt*16+c
    short8 ap = *(const short8*)((const char*)PsW + c * 80 + 16 * g);
    o[0] = __builtin_amdgcn_mfma_f32_16x16x32_bf16(ap, b.v0, o[0], 0, 0, 0);
    o[1] = __builtin_amdgcn_mfma_f32_16x16x32_bf16(ap, b.v1, o[1], 0, 0, 0);
    o[2] = __builtin_amdgcn_mfma_f32_16x16x32_bf16(ap, b.v2, o[2], 0, 0, 0);
    o[3] = __builtin_amdgcn_mfma_f32_16x16x32_bf16(ap, b.v3, o[3], 0, 0, 0);
}

__device__ __forceinline__ void attn_epilogue(float* out, const f32x4 (&o)[4], float l_run,
                                              int n, int h, int qw, int c, int g)
{
    float lr[4];
#pragma unroll
    for (int r = 0; r < 4; r++) lr[r] = __shfl(l_run, 4 * g + r);
#pragma unroll
    for (int dt = 0; dt < 4; dt++)
#pragma unroll
        for (int r = 0; r < 4; r++) {
            int q = qw + 4 * g + r;
            int d = h * HD + dt * 16 + c;
            out[((size_t)n * LQ + q) * DM + d] = o[dt][r] / lr[r];
        }
}

__global__ __launch_bounds__(64, 2) void attnk(
    const unsigned short* __restrict__ Qp, const unsigned short* __restrict__ Kp,
    const unsigned short* __restrict__ Vt, const unsigned char* __restrict__ pm,
    float* __restrict__ out)
{
    __shared__ unsigned short Ps[1280];  // two 16x32 P buffers, stride 80 B
    int lane = threadIdx.x & 63;
    // bid -> (xcd, y, xs): same (n,h) stays on one XCD (K/V slice 512 KB -> L2-resident)
    int bid = blockIdx.x;
    int xcd = bid & 7, idx = bid >> 3;
    int y = xcd * 4 + (idx & 3);        // 0..31
    int n = y >> 4, h = y & 15;
    int xs = idx >> 2;                  // 0..63
    int qwA = xs * 16, qwB = (127 - xs) * 16;
    const int c = lane & 15, g = lane >> 4, fk = g * 8;

    // valid length via popcount of padding mask
    int vlen;
    {
        const uint4* pmv = (const uint4*)(pm + (size_t)n * LK);
        uint4 a = pmv[lane * 2], b = pmv[lane * 2 + 1];
        int ones = __popc(a.x) + __popc(a.y) + __popc(a.z) + __popc(a.w)
                 + __popc(b.x) + __popc(b.y) + __popc(b.z) + __popc(b.w);
        int zeros = 32 - ones;
#pragma unroll
        for (int off = 1; off < 64; off <<= 1) zeros += __shfl_xor(zeros, off);
        vlen = zeros;
    }
    float c2 = 1.4426950408889634f / sqrtf((float)vlen);
    int kvt = (vlen + KB - 1) >> 5;
    int ntA = min(((qwA + 15) >> 5) + 1, kvt);
    int ntB = min(((qwB + 15) >> 5) + 1, kvt);

    const unsigned short* Kbase = Kp + (size_t)n * LK * DM + h * HD;
    const unsigned short* Vbase = Vt + ((size_t)n * DM + h * HD) * LK;

    const unsigned short* qA = Qp + (size_t)(n * LQ + qwA + c) * DM + h * HD;
    const unsigned short* qB = Qp + (size_t)(n * LQ + qwB + c) * DM + h * HD;
    short8 qA0 = *(const short8*)(qA + fk), qA1 = *(const short8*)(qA + 32 + fk);
    short8 qB0 = *(const short8*)(qB + fk), qB1 = *(const short8*)(qB + 32 + fk);

    f32x4 zero = {0.f, 0.f, 0.f, 0.f};
    f32x4 oA[4] = {zero, zero, zero, zero};
    f32x4 oB[4] = {zero, zero, zero, zero};
    float mA = -INFINITY, lA = 0.f, mB = -INFINITY, lB = 0.f;
    unsigned short* PsA = Ps;
    unsigned short* PsB = Ps + 640;

    KVreg b0, b1;
    ld_kv(b0, Kbase, Vbase, 0, c, fk);
    int ti = 0;
    while (true) {
        if (ti + 1 < ntB) ld_kv(b1, Kbase, Vbase, (ti + 1) * KB, c, fk);
        if (ti < ntA) phase32(b0, qA0, qA1, PsA, qwA, ti * KB, vlen, c2, oA, mA, lA, c, g);
        phase32(b0, qB0, qB1, PsB, qwB, ti * KB, vlen, c2, oB, mB, lB, c, g);
        if (++ti >= ntB) break;
        if (ti + 1 < ntB) ld_kv(b0, Kbase, Vbase, (ti + 1) * KB, c, fk);
        if (ti < ntA) phase32(b1, qA0, qA1, PsA, qwA, ti * KB, vlen, c2, oA, mA, lA, c, g);
        phase32(b1, qB0, qB1, PsB, qwB, ti * KB, vlen, c2, oB, mB, lB, c, g);
        if (++ti >= ntB) break;
    }
    attn_epilogue(out, oA, lA, n, h, qwA, c, g);
    attn_epilogue(out, oB, lB, n, h, qwB, c, g);
}

// ---------------- launch ----------------
extern "C" void kernel_launch(void* const* d_in, const int* in_sizes, int n_in,
                              void* d_out, int out_size, void* d_ws, size_t ws_size,
                              hipStream_t stream) {
    const float* query = (const float*)d_in[0];
    const float* key   = (const float*)d_in[1];
    const float* Wq    = (const float*)d_in[2];
    const float* Wk    = (const float*)d_in[3];
    const float* Wv    = (const float*)d_in[4];
    const unsigned char* pmask = (const unsigned char*)d_in[6];
    float* out = (float*)d_out;

    char* ws = (char*)d_ws;
    unsigned short* bfbase = (unsigned short*)ws;
    unsigned short* Qb  = bfbase;                          // 4096x1024
    unsigned short* Kb  = bfbase + 4194304L;               // 4096x1024
    unsigned short* Wqb = bfbase + 8388608L;
    unsigned short* Wkb = bfbase + 9437184L;
    unsigned short* Wvb = bfbase + 10485760L;
    unsigned short* Qp  = (unsigned short*)(ws + 23068672L);
    unsigned short* Kp  = (unsigned short*)(ws + 31457280L);
    unsigned short* Vp  = (unsigned short*)(ws + 39845888L);
    unsigned short* Vt  = (unsigned short*)(ws + 48234496L);   // [2][1024][2048]

    convertk<<<11264, 256, 0, stream>>>(query, key, Wq, Wk, Wv, bfbase);
    gemm3<<<dim3(32, 8, 3), 256, 0, stream>>>(Qb, Kb, Wqb, Wkb, Wvb, Qp, Kp, Vp);
    transposek<<<dim3(32, 16, 2), 256, 0, stream>>>(Vp, Vt);
    attnk<<<2048, 64, 0, stream>>>(Qp, Kp, Vt, pmask, out);
}

// Round 7
// 191.738 us; speedup vs baseline: 1.4030x; 1.2681x over previous
//
#include <hip/hip_runtime.h>
#include <math.h>

// ---------------- types ----------------
typedef __attribute__((ext_vector_type(8))) short short8;
typedef __attribute__((ext_vector_type(4))) float f32x4;

#define NB 2
#define LQ 2048
#define LK 2048
#define DM 1024
#define NH 16
#define HD 64

__device__ __forceinline__ unsigned short f2bf(float f) {
    unsigned u = __builtin_bit_cast(unsigned, f);
    u = (u + 0x7FFFu + ((u >> 16) & 1u)) >> 16;
    return (unsigned short)u;
}

__device__ __forceinline__ void gload16(const void* g, void* l) {
    __builtin_amdgcn_global_load_lds(
        (const __attribute__((address_space(1))) void*)g,
        (__attribute__((address_space(3))) void*)l, 16, 0, 0);
}

__device__ __forceinline__ unsigned cvtpk(float a, float b) {
    unsigned r;
    asm("v_cvt_pk_bf16_f32 %0, %1, %2" : "=v"(r) : "v"(a), "v"(b));
    return r;
}

// XOR-swizzled LDS accessors for [R][64] u16 tiles (row stride 128 B).
__device__ __forceinline__ short8 lds_load8(const unsigned short* base, int row, int col) {
    int byte = (row * 128 + col * 2) ^ ((row & 7) << 4);
    return *(const short8*)((const char*)base + byte);
}

// swizzled accessor for [R][32] u16 LDS tiles (row stride 64 B): slot ^= row&3
__device__ __forceinline__ short8 lds32(const unsigned short* base, int row, int col) {
    int byte = (row * 64 + col * 2) ^ ((row & 3) << 4);
    return *(const short8*)((const char*)base + byte);
}

// ---------------- convert f32 -> bf16 ----------------
__global__ __launch_bounds__(256) void convertk(
    const float* __restrict__ q, const float* __restrict__ k,
    const float* __restrict__ wq, const float* __restrict__ wk,
    const float* __restrict__ wv, unsigned short* __restrict__ dst)
{
    long i4 = (long)blockIdx.x * 256 + threadIdx.x;
    long e = i4 * 4;
    if (e >= 11534336L) return;
    const float* src; long off;
    if (e < 4194304L)       { src = q;  off = e; }
    else if (e < 8388608L)  { src = k;  off = e - 4194304L; }
    else if (e < 9437184L)  { src = wq; off = e - 8388608L; }
    else if (e < 10485760L) { src = wk; off = e - 9437184L; }
    else                    { src = wv; off = e - 10485760L; }
    float4 v = *(const float4*)(src + off);
    ushort4 r;
    r.x = f2bf(v.x); r.y = f2bf(v.y); r.z = f2bf(v.z); r.w = f2bf(v.w);
    *(ushort4*)(dst + e) = r;
}

// ---------------- projection GEMM: C = A * B^T (bf16, K=1024, BK=32, LDS dbuf) ----------------
__device__ __forceinline__ void gemm_stage(
    const unsigned short* A, const unsigned short* B,
    unsigned short* As, unsigned short* Bs,
    int bm, int bn, int k0, int wave, int srow, int scol)
{
    const int K = DM;
    int i0 = wave, i1 = wave + 4;
    gload16(A + (size_t)(bm + i0 * 16 + srow) * K + k0 + scol, As + i0 * 512);
    gload16(B + (size_t)(bn + i0 * 16 + srow) * K + k0 + scol, Bs + i0 * 512);
    gload16(A + (size_t)(bm + i1 * 16 + srow) * K + k0 + scol, As + i1 * 512);
    gload16(B + (size_t)(bn + i1 * 16 + srow) * K + k0 + scol, Bs + i1 * 512);
}

__global__ __launch_bounds__(256) void gemm3(
    const unsigned short* __restrict__ Qb, const unsigned short* __restrict__ Kb,
    const unsigned short* __restrict__ Wqb, const unsigned short* __restrict__ Wkb,
    const unsigned short* __restrict__ Wvb,
    unsigned short* __restrict__ Qp, unsigned short* __restrict__ Kp, unsigned short* __restrict__ Vp)
{
    const unsigned short *A, *B;
    unsigned short* C;
    int z = blockIdx.z;
    if (z == 0)      { A = Qb; B = Wqb; C = Qp; }
    else if (z == 1) { A = Kb; B = Wkb; C = Kp; }
    else             { A = Kb; B = Wvb; C = Vp; }
    const int NN = DM;
    __shared__ unsigned short As[2][4096];  // [128][32] swizzled
    __shared__ unsigned short Bs[2][4096];
    int t = threadIdx.x, wave = t >> 6, lane = t & 63;
    int bm = blockIdx.x * 128, bn = blockIdx.y * 128;
    int wr = (wave >> 1) * 64, wc = (wave & 1) * 64;
    int srow = lane >> 2;                        // 0..15 within 16-row stripe
    int scol = ((lane & 3) ^ (srow & 3)) << 3;   // pre-swizzled source col (elems)
    int frow = lane & 15, fk = (lane >> 4) * 8;
    f32x4 zero = {0.f, 0.f, 0.f, 0.f};
    f32x4 acc[4][4];
    for (int i = 0; i < 4; i++) for (int j = 0; j < 4; j++) acc[i][j] = zero;

    gemm_stage(A, B, As[0], Bs[0], bm, bn, 0, wave, srow, scol);
    __syncthreads();
    for (int s = 0; s < 32; s++) {
        int cur = s & 1;
        if (s + 1 < 32)
            gemm_stage(A, B, As[cur ^ 1], Bs[cur ^ 1], bm, bn, (s + 1) * 32, wave, srow, scol);
        short8 af[4], bfr[4];
#pragma unroll
        for (int i = 0; i < 4; i++) af[i]  = lds32(As[cur], wr + i * 16 + frow, fk);
#pragma unroll
        for (int j = 0; j < 4; j++) bfr[j] = lds32(Bs[cur], wc + j * 16 + frow, fk);
#pragma unroll
        for (int i = 0; i < 4; i++)
#pragma unroll
            for (int j = 0; j < 4; j++)
                acc[i][j] = __builtin_amdgcn_mfma_f32_16x16x32_bf16(af[i], bfr[j], acc[i][j], 0, 0, 0);
        __syncthreads();
    }
    int ccol = lane & 15, crow = (lane >> 4) * 4;
#pragma unroll
    for (int i = 0; i < 4; i++)
#pragma unroll
        for (int j = 0; j < 4; j++) {
            int col = bn + wc + j * 16 + ccol;
#pragma unroll
            for (int r = 0; r < 4; r++) {
                int row = bm + wr + i * 16 + crow + r;
                C[(size_t)row * NN + col] = f2bf(acc[i][j][r]);
            }
        }
}

// ---------------- transpose V (per sentence 2048x1024 -> 1024x2048) ----------------
__global__ __launch_bounds__(256) void transposek(const unsigned short* __restrict__ V,
                                                  unsigned short* __restrict__ Vt)
{
    __shared__ unsigned short tile[64][65];
    int n = blockIdx.z;
    int k0 = blockIdx.x * 64, d0 = blockIdx.y * 64;
    int t = threadIdx.x;
#pragma unroll
    for (int it = 0; it < 2; it++) {
        int r = (t >> 3) + it * 32, c = (t & 7) * 8;
        short8 v = *(const short8*)&V[((size_t)(n * LK + k0 + r)) * DM + d0 + c];
#pragma unroll
        for (int j = 0; j < 8; j++) tile[r][c + j] = (unsigned short)v[j];
    }
    __syncthreads();
#pragma unroll
    for (int it = 0; it < 2; it++) {
        int r2 = (t >> 3) + it * 32, c2 = (t & 7) * 8;
        short8 v;
#pragma unroll
        for (int j = 0; j < 8; j++) v[j] = (short)tile[c2 + j][r2];
        *(short8*)&Vt[((size_t)(n * DM + d0 + r2)) * LK + k0 + c2] = v;
    }
}

// ---------------- flash attention v7: 4-wave blocks, LDS-staged K/V, 4 blocks/CU ----------------
// Block = 4 waves x 16 q-rows = 64 q-rows sharing each staged 64-k tile (L2 traffic /4 vs R6).
// LDS = 40960 B exactly -> 4 blocks/CU -> 4 waves/SIMD for latency hiding.
// Swapped mfma(K,Q): lane holds S-column for one q (q = qw + (lane&15)).

__device__ __forceinline__ void stage_kv64(
    const unsigned short* Kbase, const unsigned short* Vbase,
    unsigned short* KsB, unsigned short* VsB,
    int k0, int w, int srl, int scs)
{
#pragma unroll
    for (int ii = 0; ii < 2; ii++) {
        int r0 = (w + 4 * ii) * 8;   // 8-row stripe base
        gload16(Kbase + (size_t)(k0 + r0 + srl) * DM + scs, KsB + r0 * 64);
        gload16(Vbase + (size_t)(r0 + srl) * LK + k0 + scs, VsB + r0 * 64);
    }
}

__device__ __forceinline__ void softmax_pack(
    f32x4 (&sv)[4], unsigned short* PsW,
    int qw, int k0, int vlen, float c2,
    f32x4 (&o)[4], float& m_run, float& l_run, int lane)
{
    const int c = lane & 15, g = lane >> 4;
    bool full = (k0 + 63 <= qw) && (k0 + 64 <= vlen);
    if (!full) {
        int q = qw + c;
#pragma unroll
        for (int kt = 0; kt < 4; kt++)
#pragma unroll
            for (int r = 0; r < 4; r++) {
                int kg = k0 + kt * 16 + g * 4 + r;
                if (kg > q || kg >= vlen) sv[kt][r] = -INFINITY;
            }
    }
    float mx = fmaxf(fmaxf(sv[0][0], sv[0][1]), fmaxf(sv[0][2], sv[0][3]));
#pragma unroll
    for (int kt = 1; kt < 4; kt++)
        mx = fmaxf(mx, fmaxf(fmaxf(sv[kt][0], sv[kt][1]), fmaxf(sv[kt][2], sv[kt][3])));
    mx = fmaxf(mx, __shfl_xor(mx, 16));
    mx = fmaxf(mx, __shfl_xor(mx, 32));      // per-q max over tile
    // defer-max (T13): only rescale when the max grew by > 8/c2 (P bounded by 2^8)
    if (__any((mx - m_run) * c2 > 8.0f)) {
        float mn = fmaxf(m_run, mx);
        float al = __builtin_amdgcn_exp2f((m_run - mn) * c2);
        float alr[4];
#pragma unroll
        for (int r = 0; r < 4; r++) alr[r] = __shfl(al, 4 * g + r);
#pragma unroll
        for (int dt = 0; dt < 4; dt++)
#pragma unroll
            for (int r = 0; r < 4; r++) o[dt][r] *= alr[r];
        l_run *= al;
        m_run = mn;
    }
    float ssum = 0.f;
#pragma unroll
    for (int kt = 0; kt < 4; kt++)
#pragma unroll
        for (int r = 0; r < 4; r++) {
            float p = __builtin_amdgcn_exp2f((sv[kt][r] - m_run) * c2);
            sv[kt][r] = p;
            ssum += p;
        }
    ssum += __shfl_xor(ssum, 16);
    ssum += __shfl_xor(ssum, 32);
    l_run += ssum;
#pragma unroll
    for (int kt = 0; kt < 4; kt++) {
        uint2 pw;
        pw.x = cvtpk(sv[kt][0], sv[kt][1]);
        pw.y = cvtpk(sv[kt][2], sv[kt][3]);
        int byte = (c * 128 + (kt * 16 + g * 4) * 2) ^ ((c & 7) << 4);
        *(uint2*)((char*)PsW + byte) = pw;
    }
}

__device__ __forceinline__ void attn_epilogue(float* out, const f32x4 (&o)[4], float l_run,
                                              int n, int h, int qw, int c, int g)
{
    float lr[4];
#pragma unroll
    for (int r = 0; r < 4; r++) lr[r] = __shfl(l_run, 4 * g + r);
#pragma unroll
    for (int dt = 0; dt < 4; dt++)
#pragma unroll
        for (int r = 0; r < 4; r++) {
            int q = qw + 4 * g + r;
            int d = h * HD + dt * 16 + c;
            out[((size_t)n * LQ + q) * DM + d] = o[dt][r] / lr[r];
        }
}

__global__ __launch_bounds__(256, 4) void attnk(
    const unsigned short* __restrict__ Qp, const unsigned short* __restrict__ Kp,
    const unsigned short* __restrict__ Vt, const unsigned char* __restrict__ pm,
    float* __restrict__ out)
{
    __shared__ unsigned short Ks[2][4096];   // [64 k][64 d] swizzled, dbuf
    __shared__ unsigned short Vs[2][4096];   // [64 d][64 k] swizzled, dbuf
    __shared__ unsigned short Ps[4][1024];   // per-wave [16 q][64 k] swizzled
    int t = threadIdx.x, w = t >> 6, lane = t & 63;
    int bid = blockIdx.x;
    // (n,h): bits 0-4 -> same (n,h) on one XCD-ish; qc: balanced per-CU rounds
    int nh = (bid & 7) * 4 + ((bid >> 3) & 3);
    int n = nh >> 4, h = nh & 15;
    int jj = (bid >> 5) & 7, rr = bid >> 8;
    int qc = (rr == 0) ? 31 - jj : (rr == 1) ? 16 + jj : (rr == 2) ? 15 - jj : jj;
    int qw = qc * 64 + 16 * w;
    const int c = lane & 15, g = lane >> 4, fk = g * 8;

    // valid length via popcount of padding mask
    int vlen;
    {
        const uint4* pmv = (const uint4*)(pm + (size_t)n * LK);
        uint4 a = pmv[lane * 2], b = pmv[lane * 2 + 1];
        int ones = __popc(a.x) + __popc(a.y) + __popc(a.z) + __popc(a.w)
                 + __popc(b.x) + __popc(b.y) + __popc(b.z) + __popc(b.w);
        int zeros = 32 - ones;
#pragma unroll
        for (int off = 1; off < 64; off <<= 1) zeros += __shfl_xor(zeros, off);
        vlen = zeros;
    }
    float c2 = 1.4426950408889634f / sqrtf((float)vlen);
    int kvt = (vlen + 63) >> 6;
    int nt = min(qc + 1, kvt);

    int srl = lane >> 3;
    int scs = ((lane & 7) ^ srl) << 3;   // pre-swizzled source column (elems)
    const unsigned short* Kbase = Kp + (size_t)n * LK * DM + h * HD;
    const unsigned short* Vbase = Vt + ((size_t)n * DM + h * HD) * LK;

    // Q fragments (B-operand: row = lane&15 -> q = qw + c)
    const unsigned short* qp = Qp + (size_t)(n * LQ + qw + c) * DM + h * HD;
    short8 q0 = *(const short8*)(qp + fk), q1 = *(const short8*)(qp + 32 + fk);

    f32x4 zero = {0.f, 0.f, 0.f, 0.f};
    f32x4 o[4] = {zero, zero, zero, zero};
    float m_run = -INFINITY, l_run = 0.f;
    unsigned short* PsW = Ps[w];

    stage_kv64(Kbase, Vbase, Ks[0], Vs[0], 0, w, srl, scs);
    __syncthreads();

    for (int ti = 0; ti < nt; ti++) {
        int cur = ti & 1, k0 = ti * 64;
        if (ti + 1 < nt)
            stage_kv64(Kbase, Vbase, Ks[cur ^ 1], Vs[cur ^ 1], k0 + 64, w, srl, scs);

        f32x4 sv[4];
        __builtin_amdgcn_s_setprio(1);
#pragma unroll
        for (int kt = 0; kt < 4; kt++) {
            short8 kf0 = lds_load8(Ks[cur], kt * 16 + c, fk);
            short8 kf1 = lds_load8(Ks[cur], kt * 16 + c, 32 + fk);
            f32x4 z = zero;
            z = __builtin_amdgcn_mfma_f32_16x16x32_bf16(kf0, q0, z, 0, 0, 0);
            z = __builtin_amdgcn_mfma_f32_16x16x32_bf16(kf1, q1, z, 0, 0, 0);
            sv[kt] = z;
        }
        __builtin_amdgcn_s_setprio(0);

        softmax_pack(sv, PsW, qw, k0, vlen, c2, o, m_run, l_run, lane);

        __builtin_amdgcn_s_setprio(1);
#pragma unroll
        for (int ks = 0; ks < 2; ks++) {
            short8 ap = lds_load8(PsW, c, ks * 32 + fk);
#pragma unroll
            for (int dt = 0; dt < 4; dt++) {
                short8 bv = lds_load8(Vs[cur], dt * 16 + c, ks * 32 + fk);
                o[dt] = __builtin_amdgcn_mfma_f32_16x16x32_bf16(ap, bv, o[dt], 0, 0, 0);
            }
        }
        __builtin_amdgcn_s_setprio(0);
        __syncthreads();   // staging of next tile drained + all waves done with cur
    }
    attn_epilogue(out, o, l_run, n, h, qw, c, g);
}

// ---------------- launch ----------------
extern "C" void kernel_launch(void* const* d_in, const int* in_sizes, int n_in,
                              void* d_out, int out_size, void* d_ws, size_t ws_size,
                              hipStream_t stream) {
    const float* query = (const float*)d_in[0];
    const float* key   = (const float*)d_in[1];
    const float* Wq    = (const float*)d_in[2];
    const float* Wk    = (const float*)d_in[3];
    const float* Wv    = (const float*)d_in[4];
    const unsigned char* pmask = (const unsigned char*)d_in[6];
    float* out = (float*)d_out;

    char* ws = (char*)d_ws;
    unsigned short* bfbase = (unsigned short*)ws;
    unsigned short* Qb  = bfbase;                          // 4096x1024
    unsigned short* Kb  = bfbase + 4194304L;               // 4096x1024
    unsigned short* Wqb = bfbase + 8388608L;
    unsigned short* Wkb = bfbase + 9437184L;
    unsigned short* Wvb = bfbase + 10485760L;
    unsigned short* Qp  = (unsigned short*)(ws + 23068672L);
    unsigned short* Kp  = (unsigned short*)(ws + 31457280L);
    unsigned short* Vp  = (unsigned short*)(ws + 39845888L);
    unsigned short* Vt  = (unsigned short*)(ws + 48234496L);   // [2][1024][2048]

    convertk<<<11264, 256, 0, stream>>>(query, key, Wq, Wk, Wv, bfbase);
    gemm3<<<dim3(32, 8, 3), 256, 0, stream>>>(Qb, Kb, Wqb, Wkb, Wvb, Qp, Kp, Vp);
    transposek<<<dim3(32, 16, 2), 256, 0, stream>>>(Vp, Vt);
    attnk<<<1024, 256, 0, stream>>>(Qp, Kp, Vt, pmask, out);
}